// Round 18
// baseline (209.455 us; speedup 1.0000x reference)
//
#include <hip/hip_runtime.h>
#include <hip/hip_bf16.h>

typedef __bf16 bf16_t;
typedef __bf16 bf16x8 __attribute__((ext_vector_type(8)));
typedef float  f32x4  __attribute__((ext_vector_type(4)));

#define DK 1024   // d_in  (K)
#define DN 1024   // d_out (N)
#define RNK 32
#define BM 128
#define BN 512
#define BK 32
#define NKT 32

// ---- Pass 1: W_eff = W + C @ V_r^T, bf16, PRE-SWIZZLED (R7 layout) ---------
__global__ void weff_kernel(const float* __restrict__ W,
                            const float* __restrict__ Vr,
                            const float* __restrict__ C,
                            bf16_t* __restrict__ WeffSw)
{
    const int o  = blockIdx.x;
    const int g  = threadIdx.x;
    const int d0 = g * 8;

    f32x4 cv[8];
#pragma unroll
    for (int q = 0; q < 8; ++q) cv[q] = *(const f32x4*)(C + o * RNK + q * 4);

    const f32x4* wrow = (const f32x4*)(W + (size_t)o * DK + d0);
    f32x4 w0 = wrow[0], w1 = wrow[1];
    float acc[8];
#pragma unroll
    for (int e = 0; e < 4; ++e) { acc[e] = w0[e]; acc[4 + e] = w1[e]; }

#pragma unroll
    for (int e = 0; e < 8; ++e) {
        const f32x4* vre = (const f32x4*)(Vr + (size_t)(d0 + e) * RNK);
        float s = 0.f;
#pragma unroll
        for (int q = 0; q < 8; ++q) {
            f32x4 v = vre[q];
            s += cv[q][0] * v[0] + cv[q][1] * v[1] + cv[q][2] * v[2] + cv[q][3] * v[3];
        }
        acc[e] += s;
    }

    bf16x8 out;
#pragma unroll
    for (int e = 0; e < 8; ++e) out[e] = (bf16_t)acc[e];

    const int bn = o >> 9, rloc = o & 511;
    const int kt = d0 >> 5, seg = (d0 >> 3) & 3;
    const int sw = seg ^ ((rloc >> 1) & 3);
    const size_t byte = (size_t)(bn * 32 + kt) * 32768 + rloc * 64 + (sw << 4);
    *(bf16x8*)((char*)WeffSw + byte) = out;
}

// ---- Pass 2: all-DMA GEMM. A = fp32 direct from x, TWO-PLANE 64B-row tile --
// A-tile (16KB): plane p = k-half (16 fp32 = 64B rows), 128 rows, 4 granules
// of 16B, swizzle g' = g ^ ((row>>1)&3)  -- same bank geometry as R16's
// conflict-free bf16 tile. DMA source computes inverse swizzle on row-major
// fp32 x (per-lane src, linear dest). Frags: 2x f32x4 ds_read + in-reg cvt.
// B: bf16 pre-swizzled Weff (probe-validated). Depth-2, vmcnt(6).
__global__ __launch_bounds__(512, 1) void corrlin_gemm_dma(
    const float* __restrict__ X, const bf16_t* __restrict__ WeffSw,
    const float* __restrict__ bias, float* __restrict__ Out)
{
    __shared__ __align__(16) char smem[147456];
    char* Aq0 = smem;                 // 16KB each (fp32 A tiles, 2-plane)
    char* Aq1 = smem + 16384;
    char* Aq2 = smem + 32768;
    char* Bq0 = smem + 49152;         // 32KB each (bf16 B tiles)
    char* Bq1 = smem + 81920;
    char* Bq2 = smem + 114688;

    const int tid = threadIdx.x;
    const int b0  = blockIdx.x;
    const int L  = (b0 & 7) * 128 + (b0 >> 3);   // XCD-bijective, nwg=1024
    const int bm = L >> 1;
    const int bn = L & 1;
    const int m0 = bm * BM;

    const int lane = tid & 63;
    const int wn   = tid >> 6;

    f32x4 acc[8][4] = {};

    // A DMA: 1024 granules of 16B; dest granule d -> p=d>>9, sr=(d>>2)&127,
    // g = (d&3) ^ ((sr>>1)&3); src = x[m0+sr][kt*32 + p*16 + g*4 .. +4).
    auto issueA = [&](int kt, char* Ab) {
#pragma unroll
        for (int c = 0; c < 2; ++c) {
            const int d  = wn * 128 + c * 64 + lane;
            const int p  = d >> 9;
            const int sr = (d >> 2) & 127;
            const int g  = (d & 3) ^ ((sr >> 1) & 3);
            const float* src = X + (size_t)(m0 + sr) * DK + kt * 32 + p * 16 + g * 4;
            __builtin_amdgcn_global_load_lds(
                (const __attribute__((address_space(1))) void*)src,
                (__attribute__((address_space(3))) void*)(Ab + wn * 2048 + c * 1024),
                16, 0, 0);
        }
    };
    auto issueB = [&](int kt, char* Bb) {
        const char* g = (const char*)WeffSw + (size_t)(bn * 32 + kt) * 32768;
#pragma unroll
        for (int c = 0; c < 4; ++c) {
            const int lin = c * 8192 + wn * 1024;
            __builtin_amdgcn_global_load_lds(
                (const __attribute__((address_space(1))) void*)(g + lin + lane * 16),
                (__attribute__((address_space(3))) void*)(Bb + lin),
                16, 0, 0);
        }
    };
    auto readB = [&](const char* Bc, bf16x8* bfr) {
        const int kb = lane >> 4;
#pragma unroll
        for (int nf = 0; nf < 4; ++nf) {
            const int row = wn * 64 + nf * 16 + (lane & 15);
            bfr[nf] = *(const bf16x8*)(Bc + row * 64 + ((kb ^ ((row >> 1) & 3)) << 4));
        }
    };
    auto compute_h = [&](const char* Ac, int h, const bf16x8* bfr) {
        bf16x8 af[4];
        const int kb = lane >> 4;
        const int p  = kb >> 1;       // K-half plane
        const int a  = kb & 1;        // quarter within plane
#pragma unroll
        for (int i = 0; i < 4; ++i) {
            const int row = (h * 4 + i) * 16 + (lane & 15);
            const int q = (row >> 1) & 3;
            f32x4 v0 = *(const f32x4*)(Ac + p * 8192 + row * 64 + (((2 * a)     ^ q) << 4));
            f32x4 v1 = *(const f32x4*)(Ac + p * 8192 + row * 64 + (((2 * a + 1) ^ q) << 4));
#pragma unroll
            for (int j = 0; j < 4; ++j) { af[i][j] = (bf16_t)v0[j]; af[i][4 + j] = (bf16_t)v1[j]; }
        }
        __builtin_amdgcn_s_setprio(1);
#pragma unroll
        for (int i = 0; i < 4; ++i)
#pragma unroll
            for (int nf = 0; nf < 4; ++nf)
                acc[h * 4 + i][nf] = __builtin_amdgcn_mfma_f32_16x16x32_bf16(
                    af[i], bfr[nf], acc[h * 4 + i][nf], 0, 0, 0);
        __builtin_amdgcn_s_setprio(0);
    };

    // steady-state iteration (t+2 <= 31 guaranteed by caller)
    auto iterM = [&](int t, const char* Ac, const char* Bc, char* An2, char* Bn2) {
        issueB(t + 2, Bn2);               // 4 ops
        issueA(t + 2, An2);               // 2 ops
        bf16x8 bfr[4];
        readB(Bc, bfr);
        compute_h(Ac, 0, bfr);
        compute_h(Ac, 1, bfr);
        asm volatile("s_waitcnt vmcnt(6) lgkmcnt(0)" ::: "memory");  // drain tile t+1
        __builtin_amdgcn_s_barrier();
    };

    // ---- prologue: tiles 0,1 issued; tile 0 landed -------------------------
    issueB(0, Bq0); issueA(0, Aq0);
    issueB(1, Bq1); issueA(1, Aq1);
    asm volatile("s_waitcnt vmcnt(6)" ::: "memory");    // tile 0 complete
    __builtin_amdgcn_s_barrier();

    // main: t = 0..29, 3-cyclic buffers, guard-free
    for (int t = 0; t < 30; t += 3) {
        iterM(t,     Aq0, Bq0, Aq2, Bq2);
        iterM(t + 1, Aq1, Bq1, Aq0, Bq0);
        iterM(t + 2, Aq2, Bq2, Aq1, Bq1);
    }
    // t = 30: no issue; drain tile 31
    {
        bf16x8 bfr[4];
        readB(Bq0, bfr);
        compute_h(Aq0, 0, bfr);
        compute_h(Aq0, 1, bfr);
        asm volatile("s_waitcnt vmcnt(0) lgkmcnt(0)" ::: "memory");
        __builtin_amdgcn_s_barrier();
    }
    // t = 31
    {
        bf16x8 bfr[4];
        readB(Bq1, bfr);
        compute_h(Aq1, 0, bfr);
        compute_h(Aq1, 1, bfr);
    }
    __syncthreads();                 // LDS free for epilogue reuse

    // ---- epilogue: per-wave LDS transpose -> full-line f32x4 stores --------
    float* tb = (float*)smem + wn * 1280;
    const int nbase = bn * BN + wn * 64;
    float bv[4];
#pragma unroll
    for (int nf = 0; nf < 4; ++nf) bv[nf] = bias[nbase + nf * 16 + (lane & 15)];

#pragma unroll
    for (int mf = 0; mf < 8; ++mf) {
#pragma unroll
        for (int nf = 0; nf < 4; ++nf)
#pragma unroll
            for (int j = 0; j < 4; ++j) {
                const int r = (lane >> 4) * 4 + j;
                const int c = nf * 16 + (lane & 15);
                tb[r * 80 + c] = acc[mf][nf][j] + bv[nf];
            }
        __syncthreads();
#pragma unroll
        for (int jj = 0; jj < 4; ++jj) {
            const int rr = jj * 4 + (lane >> 4);
            const int cc = (lane & 15) * 4;
            f32x4 v = *(const f32x4*)&tb[rr * 80 + cc];
            *(f32x4*)&Out[(size_t)(m0 + mf * 16 + rr) * DN + nbase + cc] = v;
        }
        __syncthreads();
    }
}

extern "C" void kernel_launch(void* const* d_in, const int* in_sizes, int n_in,
                              void* d_out, int out_size, void* d_ws, size_t ws_size,
                              hipStream_t stream) {
    const float* x  = (const float*)d_in[0];
    const float* W  = (const float*)d_in[1];
    const float* b  = (const float*)d_in[2];
    const float* Vr = (const float*)d_in[3];
    const float* C  = (const float*)d_in[4];
    float* out = (float*)d_out;

    const int M = in_sizes[0] / DK;            // 65536
    bf16_t* WeffSw = (bf16_t*)d_ws;            // 2 MB pre-swizzled W_eff

    weff_kernel<<<DN, 128, 0, stream>>>(W, Vr, C, WeffSw);

    const int mtiles = M / BM;                 // 512
    const int nwg = mtiles * (DN / BN);        // 1024
    corrlin_gemm_dma<<<nwg, 512, 0, stream>>>(x, WeffSw, b, out);
}

// Round 19
// 204.745 us; speedup vs baseline: 1.0230x; 1.0230x over previous
//
#include <hip/hip_runtime.h>
#include <hip/hip_bf16.h>

typedef __bf16 bf16_t;
typedef __bf16 bf16x8 __attribute__((ext_vector_type(8)));
typedef float  f32x4  __attribute__((ext_vector_type(4)));

#define DK 1024   // d_in  (K)
#define DN 1024   // d_out (N)
#define RNK 32
#define BM 128
#define BN 512
#define BK 32
#define NKT 32

// ---- Pass 1: W_eff = W + C @ V_r^T, bf16, PRE-SWIZZLED (R7 layout) ---------
__global__ void weff_kernel(const float* __restrict__ W,
                            const float* __restrict__ Vr,
                            const float* __restrict__ C,
                            bf16_t* __restrict__ WeffSw)
{
    const int o  = blockIdx.x;
    const int g  = threadIdx.x;
    const int d0 = g * 8;

    f32x4 cv[8];
#pragma unroll
    for (int q = 0; q < 8; ++q) cv[q] = *(const f32x4*)(C + o * RNK + q * 4);

    const f32x4* wrow = (const f32x4*)(W + (size_t)o * DK + d0);
    f32x4 w0 = wrow[0], w1 = wrow[1];
    float acc[8];
#pragma unroll
    for (int e = 0; e < 4; ++e) { acc[e] = w0[e]; acc[4 + e] = w1[e]; }

#pragma unroll
    for (int e = 0; e < 8; ++e) {
        const f32x4* vre = (const f32x4*)(Vr + (size_t)(d0 + e) * RNK);
        float s = 0.f;
#pragma unroll
        for (int q = 0; q < 8; ++q) {
            f32x4 v = vre[q];
            s += cv[q][0] * v[0] + cv[q][1] * v[1] + cv[q][2] * v[2] + cv[q][3] * v[3];
        }
        acc[e] += s;
    }

    bf16x8 out;
#pragma unroll
    for (int e = 0; e < 8; ++e) out[e] = (bf16_t)acc[e];

    const int bn = o >> 9, rloc = o & 511;
    const int kt = d0 >> 5, seg = (d0 >> 3) & 3;
    const int sw = seg ^ ((rloc >> 1) & 3);
    const size_t byte = (size_t)(bn * 32 + kt) * 32768 + rloc * 64 + (sw << 4);
    *(bf16x8*)((char*)WeffSw + byte) = out;
}

// ---- Pass 2: fp32-direct DMA + in-LDS convert + bf16 compute core ----------
// A: fp32 DMA'd from row-major x (per-lane swizzled src, R17 form) into
//    3-cyclic fp32 buffers (issued 3-ahead, cold stream); converted LDS->LDS
//    (1-ahead) into R16's measured-conflict-free bf16 layout; compute reads
//    bf16 frags (R16 pattern). B: bf16 pre-swizzled Weff, 2-cyclic, 1-ahead.
// Steady end-of-iter wait: vmcnt(2) (drain B(t+1) + A_fp32(t+1); keep A(t+3)).
__global__ __launch_bounds__(512, 1) void corrlin_gemm_dma(
    const float* __restrict__ X, const bf16_t* __restrict__ WeffSw,
    const float* __restrict__ bias, float* __restrict__ Out)
{
    __shared__ __align__(16) char smem[131072];
    char* Af0 = smem;                 // fp32 A staging, 16KB each
    char* Af1 = smem + 16384;
    char* Af2 = smem + 32768;
    char* Ab0 = smem + 49152;         // bf16 A converted, 8KB each
    char* Ab1 = smem + 57344;
    char* Bq0 = smem + 65536;         // B, 32KB each
    char* Bq1 = smem + 98304;

    const int tid = threadIdx.x;
    const int b0  = blockIdx.x;
    const int L  = (b0 & 7) * 128 + (b0 >> 3);   // XCD-bijective, nwg=1024
    const int bm = L >> 1;
    const int bn = L & 1;
    const int m0 = bm * BM;

    const int lane = tid & 63;
    const int wn   = tid >> 6;

    f32x4 acc[8][4] = {};

    // A DMA (fp32, 128B rows, slot = g ^ (row&7)): dest granule d ->
    // row = d>>3, g = (d&7)^(row&7); src = x[m0+row][kt*32 + g*4 .. +4).
    auto issueA = [&](int kt, char* Af) {
#pragma unroll
        for (int c = 0; c < 2; ++c) {
            const int d   = wn * 128 + c * 64 + lane;
            const int row = d >> 3;
            const int g   = (d & 7) ^ (row & 7);
            const float* src = X + (size_t)(m0 + row) * DK + kt * 32 + g * 4;
            __builtin_amdgcn_global_load_lds(
                (const __attribute__((address_space(1))) void*)src,
                (__attribute__((address_space(3))) void*)(Af + wn * 2048 + c * 1024),
                16, 0, 0);
        }
    };
    auto issueB = [&](int kt, char* Bb) {
        const char* g = (const char*)WeffSw + (size_t)(bn * 32 + kt) * 32768;
#pragma unroll
        for (int c = 0; c < 4; ++c) {
            const int lin = c * 8192 + wn * 1024;
            __builtin_amdgcn_global_load_lds(
                (const __attribute__((address_space(1))) void*)(g + lin + lane * 16),
                (__attribute__((address_space(3))) void*)(Bb + lin),
                16, 0, 0);
        }
    };
    // LDS->LDS convert: thread -> (row = tid>>2, qs = tid&3). Reads fp32
    // granules {2qs, 2qs+1} (slot g^(row&7)); writes bf16 granule qs at
    // slot qs^((row>>1)&3) (R16 layout). Both patterns sequential-8 clean.
    auto convertA = [&](const char* Af, char* Abb) {
        const int row = tid >> 2;
        const int qs  = tid & 3;
        const int r7  = row & 7;
        f32x4 v0 = *(const f32x4*)(Af + row * 128 + (((2 * qs)     ^ r7) << 4));
        f32x4 v1 = *(const f32x4*)(Af + row * 128 + (((2 * qs + 1) ^ r7) << 4));
        bf16x8 v;
#pragma unroll
        for (int j = 0; j < 4; ++j) { v[j] = (bf16_t)v0[j]; v[4 + j] = (bf16_t)v1[j]; }
        *(bf16x8*)(Abb + row * 64 + ((qs ^ ((row >> 1) & 3)) << 4)) = v;
    };
    auto readB = [&](const char* Bc, bf16x8* bfr) {
        const int kb = lane >> 4;
#pragma unroll
        for (int nf = 0; nf < 4; ++nf) {
            const int row = wn * 64 + nf * 16 + (lane & 15);
            bfr[nf] = *(const bf16x8*)(Bc + row * 64 + ((kb ^ ((row >> 1) & 3)) << 4));
        }
    };
    auto compute_h = [&](const char* Abb, int h, const bf16x8* bfr) {
        bf16x8 af[4];
        const int kb = lane >> 4;
#pragma unroll
        for (int i = 0; i < 4; ++i) {
            const int row = (h * 4 + i) * 16 + (lane & 15);
            af[i] = *(const bf16x8*)(Abb + row * 64 + ((kb ^ ((row >> 1) & 3)) << 4));
        }
        __builtin_amdgcn_s_setprio(1);
#pragma unroll
        for (int i = 0; i < 4; ++i)
#pragma unroll
            for (int nf = 0; nf < 4; ++nf)
                acc[h * 4 + i][nf] = __builtin_amdgcn_mfma_f32_16x16x32_bf16(
                    af[i], bfr[nf], acc[h * 4 + i][nf], 0, 0, 0);
        __builtin_amdgcn_s_setprio(0);
    };

    // steady-state iteration (t+3 <= 31): issue B(t+1), A(t+3); convert
    // A(t+1); compute t; vmcnt(2) drains B(t+1)+Afp32(t+1), keeps A(t+3).
    auto iterM = [&](int t, const char* Bc, char* Bn, const char* Abt,
                     const char* AfN, char* AbN, char* AfI) {
        issueB(t + 1, Bn);
        issueA(t + 3, AfI);
        convertA(AfN, AbN);
        bf16x8 bfr[4];
        readB(Bc, bfr);
        compute_h(Abt, 0, bfr);
        compute_h(Abt, 1, bfr);
        asm volatile("s_waitcnt vmcnt(2) lgkmcnt(0)" ::: "memory");
        __builtin_amdgcn_s_barrier();
    };
    // tail iteration (guarded, conservative drain)
    auto iterT = [&](int t, const char* Bc, char* Bn, const char* Abt,
                     const char* AfN, char* AbN, char* AfI) {
        if (t + 1 < NKT) issueB(t + 1, Bn);
        if (t + 3 < NKT) issueA(t + 3, AfI);
        if (t + 1 < NKT) convertA(AfN, AbN);
        bf16x8 bfr[4];
        readB(Bc, bfr);
        compute_h(Abt, 0, bfr);
        compute_h(Abt, 1, bfr);
        if (t + 1 < NKT) {
            asm volatile("s_waitcnt vmcnt(0) lgkmcnt(0)" ::: "memory");
            __builtin_amdgcn_s_barrier();
        }
    };

    // ---- prologue: B(0)+A(0,1,2) issued; A(0) converted; A(1) landed -------
    issueB(0, Bq0);
    issueA(0, Af0);
    issueA(1, Af1);
    issueA(2, Af2);
    asm volatile("s_waitcnt vmcnt(4)" ::: "memory");    // B(0), A(0) landed
    __builtin_amdgcn_s_barrier();
    convertA(Af0, Ab0);
    asm volatile("s_waitcnt vmcnt(2) lgkmcnt(0)" ::: "memory");  // A(1) landed, cvt done
    __builtin_amdgcn_s_barrier();

    // main: t = 0..23, unrolled by 6 (buffer periods 2,2,3 -> lcm 6)
    for (int t = 0; t < 24; t += 6) {
        iterM(t,     Bq0, Bq1, Ab0, Af1, Ab1, Af0);   // k=0: AfN=1, AfI=0
        iterM(t + 1, Bq1, Bq0, Ab1, Af2, Ab0, Af1);   // k=1: AfN=2, AfI=1
        iterM(t + 2, Bq0, Bq1, Ab0, Af0, Ab1, Af2);   // k=2: AfN=0, AfI=2
        iterM(t + 3, Bq1, Bq0, Ab1, Af1, Ab0, Af0);   // k=3: AfN=1, AfI=0
        iterM(t + 4, Bq0, Bq1, Ab0, Af2, Ab1, Af1);   // k=4: AfN=2, AfI=1
        iterM(t + 5, Bq1, Bq0, Ab1, Af0, Ab0, Af2);   // k=5: AfN=0, AfI=2
    }
    // tail: t = 24..31 (same cyclic pattern, guarded)
    iterT(24, Bq0, Bq1, Ab0, Af1, Ab1, Af0);
    iterT(25, Bq1, Bq0, Ab1, Af2, Ab0, Af1);
    iterT(26, Bq0, Bq1, Ab0, Af0, Ab1, Af2);
    iterT(27, Bq1, Bq0, Ab1, Af1, Ab0, Af0);
    iterT(28, Bq0, Bq1, Ab0, Af2, Ab1, Af1);
    iterT(29, Bq1, Bq0, Ab1, Af0, Ab0, Af2);
    iterT(30, Bq0, Bq1, Ab0, Af1, Ab1, Af0);
    iterT(31, Bq1, Bq0, Ab1, Af2, Ab0, Af1);
    __syncthreads();                 // LDS free for epilogue reuse

    // ---- epilogue: per-wave LDS transpose -> full-line f32x4 stores --------
    float* tb = (float*)smem + wn * 1280;
    const int nbase = bn * BN + wn * 64;
    float bv[4];
#pragma unroll
    for (int nf = 0; nf < 4; ++nf) bv[nf] = bias[nbase + nf * 16 + (lane & 15)];

#pragma unroll
    for (int mf = 0; mf < 8; ++mf) {
#pragma unroll
        for (int nf = 0; nf < 4; ++nf)
#pragma unroll
            for (int j = 0; j < 4; ++j) {
                const int r = (lane >> 4) * 4 + j;
                const int c = nf * 16 + (lane & 15);
                tb[r * 80 + c] = acc[mf][nf][j] + bv[nf];
            }
        __syncthreads();
#pragma unroll
        for (int jj = 0; jj < 4; ++jj) {
            const int rr = jj * 4 + (lane >> 4);
            const int cc = (lane & 15) * 4;
            f32x4 v = *(const f32x4*)&tb[rr * 80 + cc];
            *(f32x4*)&Out[(size_t)(m0 + mf * 16 + rr) * DN + nbase + cc] = v;
        }
        __syncthreads();
    }
}

extern "C" void kernel_launch(void* const* d_in, const int* in_sizes, int n_in,
                              void* d_out, int out_size, void* d_ws, size_t ws_size,
                              hipStream_t stream) {
    const float* x  = (const float*)d_in[0];
    const float* W  = (const float*)d_in[1];
    const float* b  = (const float*)d_in[2];
    const float* Vr = (const float*)d_in[3];
    const float* C  = (const float*)d_in[4];
    float* out = (float*)d_out;

    const int M = in_sizes[0] / DK;            // 65536
    bf16_t* WeffSw = (bf16_t*)d_ws;            // 2 MB pre-swizzled W_eff

    weff_kernel<<<DN, 128, 0, stream>>>(W, Vr, C, WeffSw);

    const int mtiles = M / BM;                 // 512
    const int nwg = mtiles * (DN / BN);        // 1024
    corrlin_gemm_dma<<<nwg, 512, 0, stream>>>(x, WeffSw, b, out);
}